// Round 2
// baseline (1608.819 us; speedup 1.0000x reference)
//
#include <hip/hip_runtime.h>
#include <hip/hip_bf16.h>
#include <cstddef>

#define BB 2
#define LL 4096
#define DM 1024
#define DI 2048
#define NST 16
#define BLR (BB*LL)      // 8192 rows of (b,l)
#define NCH 64           // chunks for the scan
#define CHK (LL/NCH)     // 64 steps per chunk

// ---------------- GEMM: C[M,N] = A[M,K] * B[N,K]^T (A row-stride lda) ----------
__global__ __launch_bounds__(256)
void gemm_bt_f32(const float* __restrict__ A, const float* __restrict__ B,
                 float* __restrict__ C, int M, int N, int K, int lda)
{
  __shared__ float As[16][132];   // [k][m], padded
  __shared__ float Bs[16][132];   // [k][n], padded
  const int m0 = blockIdx.y * 128;
  const int n0 = blockIdx.x * 128;
  const int t  = threadIdx.x;
  const int tm = t >> 2;          // 0..63
  const int tk = (t & 3) << 2;    // 0,4,8,12
  const int tx = t & 15;          // n microtile group
  const int ty = t >> 4;          // m microtile group
  float acc[8][8];
  #pragma unroll
  for (int i = 0; i < 8; ++i)
    #pragma unroll
    for (int j = 0; j < 8; ++j) acc[i][j] = 0.f;

  for (int k0 = 0; k0 < K; k0 += 16) {
    float4 a0 = *(const float4*)(A + (size_t)(m0 + tm) * lda + k0 + tk);
    float4 a1 = *(const float4*)(A + (size_t)(m0 + tm + 64) * lda + k0 + tk);
    float4 b0 = *(const float4*)(B + (size_t)(n0 + tm) * K + k0 + tk);
    float4 b1 = *(const float4*)(B + (size_t)(n0 + tm + 64) * K + k0 + tk);
    __syncthreads();
    As[tk+0][tm] = a0.x; As[tk+1][tm] = a0.y; As[tk+2][tm] = a0.z; As[tk+3][tm] = a0.w;
    As[tk+0][tm+64] = a1.x; As[tk+1][tm+64] = a1.y; As[tk+2][tm+64] = a1.z; As[tk+3][tm+64] = a1.w;
    Bs[tk+0][tm] = b0.x; Bs[tk+1][tm] = b0.y; Bs[tk+2][tm] = b0.z; Bs[tk+3][tm] = b0.w;
    Bs[tk+0][tm+64] = b1.x; Bs[tk+1][tm+64] = b1.y; Bs[tk+2][tm+64] = b1.z; Bs[tk+3][tm+64] = b1.w;
    __syncthreads();
    #pragma unroll
    for (int k = 0; k < 16; ++k) {
      float4 av0 = *(const float4*)&As[k][ty*8];
      float4 av1 = *(const float4*)&As[k][ty*8+4];
      float4 bv0 = *(const float4*)&Bs[k][tx*8];
      float4 bv1 = *(const float4*)&Bs[k][tx*8+4];
      float a[8] = {av0.x, av0.y, av0.z, av0.w, av1.x, av1.y, av1.z, av1.w};
      float b[8] = {bv0.x, bv0.y, bv0.z, bv0.w, bv1.x, bv1.y, bv1.z, bv1.w};
      #pragma unroll
      for (int i = 0; i < 8; ++i)
        #pragma unroll
        for (int j = 0; j < 8; ++j)
          acc[i][j] = fmaf(a[i], b[j], acc[i][j]);
    }
  }
  #pragma unroll
  for (int i = 0; i < 8; ++i) {
    float4 c0 = make_float4(acc[i][0], acc[i][1], acc[i][2], acc[i][3]);
    float4 c1 = make_float4(acc[i][4], acc[i][5], acc[i][6], acc[i][7]);
    float* p = C + (size_t)(m0 + ty*8 + i) * N + n0 + tx*8;
    *(float4*)p     = c0;
    *(float4*)(p+4) = c1;
  }
}

// ---------------- depthwise causal conv(4) + SiLU ----------------
__global__ __launch_bounds__(256)
void conv_silu_k(const float* __restrict__ xz, const float* __restrict__ cw,
                 const float* __restrict__ cb, float* __restrict__ xc)
{
  size_t idx = (size_t)blockIdx.x * 256 + threadIdx.x;   // over BLR*DI
  int d   = (int)(idx & (DI-1));
  size_t bl = idx >> 11;
  int tt  = (int)(bl & (LL-1));
  float4 w = *(const float4*)(cw + (size_t)d*4);
  float acc = cb[d];
  const float* xp = xz + bl*(size_t)(2*DI) + d;
  const ptrdiff_t st = 2*DI;
  acc = fmaf(w.w, xp[0], acc);                      // k=3 -> t
  if (tt >= 1) acc = fmaf(w.z, xp[-st],   acc);     // k=2 -> t-1
  if (tt >= 2) acc = fmaf(w.y, xp[-2*st], acc);     // k=1 -> t-2
  if (tt >= 3) acc = fmaf(w.x, xp[-3*st], acc);     // k=0 -> t-3
  float sg = 1.f/(1.f + __expf(-acc));
  xc[idx] = acc * sg;
}

// ---------------- zero a float buffer (n multiple of 1024) ----------------
__global__ __launch_bounds__(256)
void zero_k(float* __restrict__ p)
{
  size_t i = ((size_t)blockIdx.x * 256 + threadIdx.x) * 4;
  *(float4*)(p + i) = make_float4(0.f, 0.f, 0.f, 0.f);
}

// ---------------- x_proj GEMM: (BLR,96) = xc(BLR,2048) * W(96,2048)^T, split-K --
__global__ __launch_bounds__(256)
void xproj_k(const float* __restrict__ A, const float* __restrict__ W,
             float* __restrict__ out)
{
  __shared__ float As[16][132];
  __shared__ float Bs[16][100];
  const int m0  = blockIdx.x * 128;
  const int kc0 = blockIdx.y * 256;
  const int t  = threadIdx.x;
  const int tm = t >> 2;
  const int tk = (t & 3) << 2;
  const int tx = t & 15;   // 16 col groups of 6
  const int ty = t >> 4;   // 16 row groups of 8
  float acc[8][6];
  #pragma unroll
  for (int i = 0; i < 8; ++i)
    #pragma unroll
    for (int j = 0; j < 6; ++j) acc[i][j] = 0.f;

  for (int k0 = kc0; k0 < kc0 + 256; k0 += 16) {
    float4 a0 = *(const float4*)(A + (size_t)(m0 + tm) * DI + k0 + tk);
    float4 a1 = *(const float4*)(A + (size_t)(m0 + tm + 64) * DI + k0 + tk);
    float4 b0 = *(const float4*)(W + (size_t)tm * DI + k0 + tk);
    float4 b1 = make_float4(0.f,0.f,0.f,0.f);
    bool hasb1 = (tm < 32);
    if (hasb1) b1 = *(const float4*)(W + (size_t)(tm + 64) * DI + k0 + tk);
    __syncthreads();
    As[tk+0][tm] = a0.x; As[tk+1][tm] = a0.y; As[tk+2][tm] = a0.z; As[tk+3][tm] = a0.w;
    As[tk+0][tm+64] = a1.x; As[tk+1][tm+64] = a1.y; As[tk+2][tm+64] = a1.z; As[tk+3][tm+64] = a1.w;
    Bs[tk+0][tm] = b0.x; Bs[tk+1][tm] = b0.y; Bs[tk+2][tm] = b0.z; Bs[tk+3][tm] = b0.w;
    if (hasb1) {
      Bs[tk+0][tm+64] = b1.x; Bs[tk+1][tm+64] = b1.y; Bs[tk+2][tm+64] = b1.z; Bs[tk+3][tm+64] = b1.w;
    }
    __syncthreads();
    #pragma unroll
    for (int k = 0; k < 16; ++k) {
      float4 av0 = *(const float4*)&As[k][ty*8];
      float4 av1 = *(const float4*)&As[k][ty*8+4];
      float a[8] = {av0.x, av0.y, av0.z, av0.w, av1.x, av1.y, av1.z, av1.w};
      float2 p0 = *(const float2*)&Bs[k][tx*6];
      float2 p1 = *(const float2*)&Bs[k][tx*6+2];
      float2 p2 = *(const float2*)&Bs[k][tx*6+4];
      float b[6] = {p0.x, p0.y, p1.x, p1.y, p2.x, p2.y};
      #pragma unroll
      for (int i = 0; i < 8; ++i)
        #pragma unroll
        for (int j = 0; j < 6; ++j)
          acc[i][j] = fmaf(a[i], b[j], acc[i][j]);
    }
  }
  #pragma unroll
  for (int i = 0; i < 8; ++i)
    #pragma unroll
    for (int j = 0; j < 6; ++j)
      atomicAdd(&out[(size_t)(m0 + ty*8 + i) * 96 + tx*6 + j], acc[i][j]);
}

// ------- dt = softplus(dbl[:, :64] * Wdt^T + bdt), written into x-half of xz ----
__global__ __launch_bounds__(256)
void dtproj_k(const float* __restrict__ dbl, const float* __restrict__ Wdt,
              const float* __restrict__ bdt, float* __restrict__ xz)
{
  const int bl0 = blockIdx.x * 32;
  const int d   = blockIdx.y * 256 + threadIdx.x;
  const int t   = threadIdx.x;
  __shared__ float rows[32][64];
  #pragma unroll
  for (int p = 0; p < 8; ++p) {
    int i = p*256 + t;
    int r = i >> 6, k = i & 63;
    rows[r][k] = dbl[(size_t)(bl0 + r) * 96 + k];
  }
  float4 w[16];
  #pragma unroll
  for (int q = 0; q < 16; ++q) w[q] = *(const float4*)(Wdt + (size_t)d*64 + q*4);
  float bias = bdt[d];
  __syncthreads();
  for (int r = 0; r < 32; ++r) {
    float s = bias;
    #pragma unroll
    for (int q = 0; q < 16; ++q) {
      float4 rv = *(const float4*)&rows[r][q*4];
      s = fmaf(rv.x, w[q].x, s); s = fmaf(rv.y, w[q].y, s);
      s = fmaf(rv.z, w[q].z, s); s = fmaf(rv.w, w[q].w, s);
    }
    float sp = (s > 20.f) ? s : log1pf(__expf(s));
    xz[(size_t)(bl0 + r) * (2*DI) + d] = sp;   // dt stored in x-half (x is dead)
  }
}

// ---------------- scan pass A: per-chunk end state (h0=0) + sum(dt) -------------
// dt lives in x-half of xz (row stride 2*DI).
__global__ __launch_bounds__(256)
void scanA_k(const float* __restrict__ xz, const float* __restrict__ xc,
             const float* __restrict__ dbl, const float* __restrict__ A_log,
             float* __restrict__ hend, float* __restrict__ Sbuf)
{
  const int d = blockIdx.x * 256 + threadIdx.x;
  const int c = blockIdx.y;
  const int b = blockIdx.z;
  const int t = threadIdx.x;
  __shared__ float Bsh[CHK][NST];
  #pragma unroll
  for (int p = 0; p < 4; ++p) {
    int i = p*256 + t;
    int s = i >> 4, n = i & 15;
    Bsh[s][n] = dbl[(size_t)(b*LL + c*CHK + s) * 96 + 64 + n];
  }
  float Ar[16];
  #pragma unroll
  for (int q = 0; q < 4; ++q) {
    float4 al = *(const float4*)(A_log + (size_t)d*16 + q*4);
    Ar[q*4+0] = -__expf(al.x); Ar[q*4+1] = -__expf(al.y);
    Ar[q*4+2] = -__expf(al.z); Ar[q*4+3] = -__expf(al.w);
  }
  __syncthreads();
  float h[16];
  #pragma unroll
  for (int n = 0; n < 16; ++n) h[n] = 0.f;
  float S = 0.f;
  size_t dtb = ((size_t)b*LL + c*CHK) * (2*DI) + d;
  size_t xcb = ((size_t)b*LL + c*CHK) * DI + d;
  for (int s = 0; s < CHK; ++s) {
    float dtv = xz[dtb + (size_t)s*(2*DI)];
    float xv  = xc[xcb + (size_t)s*DI];
    S += dtv;
    float dtx = dtv * xv;
    const float4* Bp = (const float4*)&Bsh[s][0];
    #pragma unroll
    for (int q = 0; q < 4; ++q) {
      float4 bv = Bp[q];
      h[q*4+0] = fmaf(__expf(dtv*Ar[q*4+0]), h[q*4+0], dtx*bv.x);
      h[q*4+1] = fmaf(__expf(dtv*Ar[q*4+1]), h[q*4+1], dtx*bv.y);
      h[q*4+2] = fmaf(__expf(dtv*Ar[q*4+2]), h[q*4+2], dtx*bv.z);
      h[q*4+3] = fmaf(__expf(dtv*Ar[q*4+3]), h[q*4+3], dtx*bv.w);
    }
  }
  size_t o = ((size_t)b*NCH + c) * DI + d;
  float4* hp = (float4*)(hend + o*16);
  hp[0] = make_float4(h[0],h[1],h[2],h[3]);
  hp[1] = make_float4(h[4],h[5],h[6],h[7]);
  hp[2] = make_float4(h[8],h[9],h[10],h[11]);
  hp[3] = make_float4(h[12],h[13],h[14],h[15]);
  Sbuf[o] = S;
}

// ---------------- scan pass B: stitch chunk boundaries (sequential over chunks) --
// After this, hend slot c holds the prefix state through chunk c (= h0 of chunk c+1).
__global__ __launch_bounds__(256)
void scanB_k(float* __restrict__ hend, const float* __restrict__ Sbuf,
             const float* __restrict__ A_log)
{
  int idx = blockIdx.x * 256 + threadIdx.x;   // BB*DI*16
  int n = idx & 15;
  int d = (idx >> 4) & (DI-1);
  int b = idx >> 15;
  float An = -__expf(A_log[(size_t)d*16 + n]);
  float carry = 0.f;
  for (int c = 0; c < NCH-1; ++c) {
    size_t o = ((size_t)b*NCH + c) * DI + d;
    float he = hend[o*16 + n];
    float Sc = Sbuf[o];
    carry = fmaf(__expf(An*Sc), carry, he);
    hend[o*16 + n] = carry;
  }
}

// ---------------- scan pass C: replay with true h0, fuse y+xc*D and *silu(z) ----
// dt is read from x-half of xz and overwritten in place with out_z; z from z-half.
__global__ __launch_bounds__(256)
void scanC_k(float* __restrict__ xz, const float* __restrict__ xc,
             const float* __restrict__ dbl, const float* __restrict__ A_log,
             const float* __restrict__ Dv, const float* __restrict__ hend)
{
  const int d = blockIdx.x * 256 + threadIdx.x;
  const int c = blockIdx.y;
  const int b = blockIdx.z;
  const int t = threadIdx.x;
  __shared__ float Bsh[CHK][NST];
  __shared__ float Csh[CHK][NST];
  #pragma unroll
  for (int p = 0; p < 4; ++p) {
    int i = p*256 + t;
    int s = i >> 4, n = i & 15;
    size_t row = (size_t)(b*LL + c*CHK + s) * 96;
    Bsh[s][n] = dbl[row + 64 + n];
    Csh[s][n] = dbl[row + 80 + n];
  }
  float Ar[16];
  #pragma unroll
  for (int q = 0; q < 4; ++q) {
    float4 al = *(const float4*)(A_log + (size_t)d*16 + q*4);
    Ar[q*4+0] = -__expf(al.x); Ar[q*4+1] = -__expf(al.y);
    Ar[q*4+2] = -__expf(al.z); Ar[q*4+3] = -__expf(al.w);
  }
  float Dd = Dv[d];
  float h[16];
  if (c == 0) {
    #pragma unroll
    for (int n = 0; n < 16; ++n) h[n] = 0.f;
  } else {
    size_t o = ((size_t)b*NCH + (c-1)) * DI + d;
    const float4* hp = (const float4*)(hend + o*16);
    float4 h0 = hp[0], h1 = hp[1], h2 = hp[2], h3 = hp[3];
    h[0]=h0.x; h[1]=h0.y; h[2]=h0.z; h[3]=h0.w;
    h[4]=h1.x; h[5]=h1.y; h[6]=h1.z; h[7]=h1.w;
    h[8]=h2.x; h[9]=h2.y; h[10]=h2.z; h[11]=h2.w;
    h[12]=h3.x; h[13]=h3.y; h[14]=h3.z; h[15]=h3.w;
  }
  __syncthreads();
  size_t base = ((size_t)b*LL + c*CHK) * (2*DI) + d;   // dt / out_z position
  size_t xcb  = ((size_t)b*LL + c*CHK) * DI + d;
  for (int s = 0; s < CHK; ++s) {
    float dtv = xz[base + (size_t)s*(2*DI)];
    float xv  = xc[xcb + (size_t)s*DI];
    float zv  = xz[base + (size_t)s*(2*DI) + DI];
    float dtx = dtv * xv;
    float y = 0.f;
    const float4* Bp = (const float4*)&Bsh[s][0];
    const float4* Cp = (const float4*)&Csh[s][0];
    #pragma unroll
    for (int q = 0; q < 4; ++q) {
      float4 bv = Bp[q], cv = Cp[q];
      h[q*4+0] = fmaf(__expf(dtv*Ar[q*4+0]), h[q*4+0], dtx*bv.x); y = fmaf(h[q*4+0], cv.x, y);
      h[q*4+1] = fmaf(__expf(dtv*Ar[q*4+1]), h[q*4+1], dtx*bv.y); y = fmaf(h[q*4+1], cv.y, y);
      h[q*4+2] = fmaf(__expf(dtv*Ar[q*4+2]), h[q*4+2], dtx*bv.z); y = fmaf(h[q*4+2], cv.z, y);
      h[q*4+3] = fmaf(__expf(dtv*Ar[q*4+3]), h[q*4+3], dtx*bv.w); y = fmaf(h[q*4+3], cv.w, y);
    }
    y = fmaf(xv, Dd, y);
    float sg = 1.f/(1.f + __expf(-zv));
    xz[base + (size_t)s*(2*DI)] = y * (zv * sg);   // out_z in place of dt
  }
}

extern "C" void kernel_launch(void* const* d_in, const int* in_sizes, int n_in,
                              void* d_out, int out_size, void* d_ws, size_t ws_size,
                              hipStream_t stream)
{
  const float* hs   = (const float*)d_in[0];
  const float* Win  = (const float*)d_in[1];
  const float* cw   = (const float*)d_in[2];
  const float* cb   = (const float*)d_in[3];
  const float* Wx   = (const float*)d_in[4];
  const float* Wdt  = (const float*)d_in[5];
  const float* bdt  = (const float*)d_in[6];
  const float* Alog = (const float*)d_in[7];
  const float* Dv   = (const float*)d_in[8];
  const float* Wout = (const float*)d_in[9];
  float* out = (float*)d_out;

  // d_ws: xz (BLR*4096) + xc (BLR*2048)  = 192 MiB
  float* ws = (float*)d_ws;
  float* xz = ws;                              // BLR*4096
  float* xc = xz + (size_t)BLR*4096;           // BLR*2048

  // small scratch lives inside d_out (8192*1024 floats = 32 MiB), consumed
  // entirely by scanC BEFORE the final GEMM overwrites d_out.
  float* hend = out;                                   // BB*NCH*DI*16 = 4,194,304 f
  float* Sb   = hend + (size_t)BB*NCH*DI*NST;          // BB*NCH*DI    =   262,144 f
  float* dbl  = Sb + (size_t)BB*NCH*DI;                // BLR*96       =   786,432 f
                                                       // total 5,242,880 < 8,388,608

  // 1) xz = hs * Win^T   (M=8192, N=4096, K=1024)
  gemm_bt_f32<<<dim3(4096/128, BLR/128), 256, 0, stream>>>(hs, Win, xz, BLR, 4096, 1024, 1024);
  // 2) conv + silu -> xc
  conv_silu_k<<<(BLR*DI)/256, 256, 0, stream>>>(xz, cw, cb, xc);
  // 3) dbl = xc * Wx^T  (split-K with atomics)
  zero_k<<<(BLR*96)/1024, 256, 0, stream>>>(dbl);
  xproj_k<<<dim3(BLR/128, 8), 256, 0, stream>>>(xc, Wx, dbl);
  // 4) dt = softplus(dbl[:, :64] * Wdt^T + bdt) -> x-half of xz
  dtproj_k<<<dim3(BLR/32, DI/256), 256, 0, stream>>>(dbl, Wdt, bdt, xz);
  // 5) scan pass A: per-chunk local end states
  scanA_k<<<dim3(DI/256, NCH, BB), 256, 0, stream>>>(xz, xc, dbl, Alog, hend, Sb);
  // 6) scan pass B: stitch chunk boundaries
  scanB_k<<<(BB*DI*NST)/256, 256, 0, stream>>>(hend, Sb, Alog);
  // 7) scan pass C: replay with true h0, fuse epilogue -> out_z (x-half of xz)
  scanC_k<<<dim3(DI/256, NCH, BB), 256, 0, stream>>>(xz, xc, dbl, Alog, Dv, hend);
  // 8) out = out_z * Wout^T  (M=8192, N=1024, K=2048, lda=4096)
  gemm_bt_f32<<<dim3(1024/128, BLR/128), 256, 0, stream>>>(xz, Wout, out, BLR, 1024, 2048, 4096);
}

// Round 3
// 813.256 us; speedup vs baseline: 1.9782x; 1.9782x over previous
//
#include <hip/hip_runtime.h>
#include <hip/hip_bf16.h>
#include <cstddef>
#include <cstdint>

#define BB 2
#define LL 4096
#define DM 1024
#define DI 2048
#define NST 16
#define BLR (BB*LL)      // 8192 rows of (b,l)
#define NCH 64           // chunks for the scan
#define CHK (LL/NCH)     // 64 steps per chunk

typedef __attribute__((ext_vector_type(8))) short bf16x8;   // 8 bf16 (4 VGPRs)
typedef __attribute__((ext_vector_type(4))) float f32x4;
typedef unsigned short u16;

__device__ __forceinline__ u16 f2bf(float x) {
  __hip_bfloat16 h = __float2bfloat16(x);
  return __builtin_bit_cast(u16, h);
}
__device__ __forceinline__ float bf2f(u16 u) {
  return __bfloat162float(__builtin_bit_cast(__hip_bfloat16, u));
}

__device__ __forceinline__ void gload_lds16(const void* g, void* l) {
  __builtin_amdgcn_global_load_lds((const __attribute__((address_space(1))) void*)g,
                                   (__attribute__((address_space(3))) void*)l, 16, 0, 0);
}

// ---- split fp32 -> [hi | lo] bf16 per row; dst row = 2K u16 ----------------
__global__ __launch_bounds__(256)
void convsplit_k(const float* __restrict__ src, u16* __restrict__ dst, int kshift)
{
  size_t i = (size_t)blockIdx.x * 256 + threadIdx.x;   // one per 4 floats
  float4 v = *(const float4*)(src + i*4);
  size_t row = i >> kshift;
  int c4 = (int)(i & ((1u << kshift) - 1));
  int K = 4 << kshift;
  u16 h0 = f2bf(v.x), h1 = f2bf(v.y), h2 = f2bf(v.z), h3 = f2bf(v.w);
  u16 l0 = f2bf(v.x - bf2f(h0)), l1 = f2bf(v.y - bf2f(h1));
  u16 l2 = f2bf(v.z - bf2f(h2)), l3 = f2bf(v.w - bf2f(h3));
  u16* p = dst + row*(size_t)(2*K) + (size_t)c4*4;
  *(ushort4*)p       = make_ushort4(h0, h1, h2, h3);
  *(ushort4*)(p + K) = make_ushort4(l0, l1, l2, l3);
}

// ---- MFMA GEMM: C[M,N] = A*B^T with bf16x3 compensation ---------------------
// A rows: [hi(K) | lo(K)]  (APANEL=false, plain)  or  panel-interleaved
//   (APANEL=true): per 64-k panel: [hi x64 | lo x64], row stride ldaB bytes.
// B rows: [hi(K) | lo(K)] plain, row stride ldbB bytes.
// 3 passes: (Ahi,Bhi), (Alo,Bhi), (Ahi,Blo). Tile 128x128, BK=64, 4 waves.
template<bool APANEL>
__global__ __launch_bounds__(256)
void gemm_mfma(const u16* __restrict__ Ab, const u16* __restrict__ Bb,
               float* __restrict__ C, int ldaB, int ldbB, int ldc, int Kseg)
{
  __shared__ __align__(16) u16 lds[16384];   // 32 KB: A [0,16K), B [16K,32K)
  const int t = threadIdx.x;
  const int lane = t & 63, wave = t >> 6;
  const int wm = wave >> 1, wn = wave & 1;
  const int m0 = blockIdx.y << 7, n0 = blockIdx.x << 7;

  // staging constants: thread covers chunk (j*256+t); row r = j*32 + (t>>3),
  // source chunk = (t&7) ^ (r&7)  (XOR-swizzle via pre-swizzled global src)
  const int r0  = t >> 3;
  const int csw = ((t & 7) ^ (r0 & 7)) << 4;   // byte offset of source chunk

  f32x4 acc[4][4];
  #pragma unroll
  for (int m = 0; m < 4; ++m)
    #pragma unroll
    for (int n = 0; n < 4; ++n) acc[m][n] = (f32x4){0.f, 0.f, 0.f, 0.f};

  char* ldsA = (char*)lds;
  char* ldsB = (char*)lds + 16384;

  const int aSegStride = APANEL ? 128 : Kseg*2;  // byte offset of lo-segment
  const int aKmul      = APANEL ? 4 : 2;         // row bytes per unit k0

  const int segAv[3] = {0, 1, 0};
  const int segBv[3] = {0, 0, 1};

  for (int pass = 0; pass < 3; ++pass) {
    const size_t aOff0 = (size_t)segAv[pass] * (size_t)aSegStride;
    const size_t bOff0 = (size_t)segBv[pass] * (size_t)(Kseg*2);
    for (int k0 = 0; k0 < Kseg; k0 += 64) {
      __syncthreads();   // previous compute done before LDS overwrite
      #pragma unroll
      for (int j = 0; j < 4; ++j) {
        const char* ga = (const char*)Ab + (size_t)(m0 + j*32 + r0)*ldaB
                         + aOff0 + (size_t)k0*aKmul + csw;
        gload_lds16(ga, ldsA + j*4096 + wave*1024);
      }
      #pragma unroll
      for (int j = 0; j < 4; ++j) {
        const char* gb = (const char*)Bb + (size_t)(n0 + j*32 + r0)*ldbB
                         + bOff0 + (size_t)k0*2 + csw;
        gload_lds16(gb, ldsB + j*4096 + wave*1024);
      }
      __syncthreads();   // vmcnt(0) drained -> LDS tiles ready
      #pragma unroll
      for (int kk = 0; kk < 2; ++kk) {
        const int kb = (kk*64 + ((lane >> 4) << 4)) ^ ((lane & 7) << 4);
        bf16x8 a[4], b[4];
        #pragma unroll
        for (int m = 0; m < 4; ++m)
          a[m] = *(const bf16x8*)(ldsA + (wm*64 + m*16 + (lane & 15))*128 + kb);
        #pragma unroll
        for (int n = 0; n < 4; ++n)
          b[n] = *(const bf16x8*)(ldsB + (wn*64 + n*16 + (lane & 15))*128 + kb);
        #pragma unroll
        for (int m = 0; m < 4; ++m)
          #pragma unroll
          for (int n = 0; n < 4; ++n)
            acc[m][n] = __builtin_amdgcn_mfma_f32_16x16x32_bf16(a[m], b[n], acc[m][n], 0, 0, 0);
      }
    }
  }
  // epilogue: C/D layout col=lane&15, row=(lane>>4)*4+i
  const int rb = (lane >> 4) << 2;
  const int cb = lane & 15;
  #pragma unroll
  for (int m = 0; m < 4; ++m) {
    #pragma unroll
    for (int n = 0; n < 4; ++n) {
      int row = m0 + wm*64 + m*16 + rb;
      int col = n0 + wn*64 + n*16 + cb;
      #pragma unroll
      for (int i = 0; i < 4; ++i)
        C[(size_t)(row + i)*ldc + col] = acc[m][n][i];
    }
  }
}

// ---------------- depthwise causal conv(4) + SiLU (x stride DI) --------------
__global__ __launch_bounds__(256)
void conv_silu_k(const float* __restrict__ x, const float* __restrict__ cw,
                 const float* __restrict__ cb, float* __restrict__ xc)
{
  size_t idx = (size_t)blockIdx.x * 256 + threadIdx.x;   // over BLR*DI
  int d   = (int)(idx & (DI-1));
  size_t bl = idx >> 11;
  int tt  = (int)(bl & (LL-1));
  float4 w = *(const float4*)(cw + (size_t)d*4);
  float acc = cb[d];
  const float* xp = x + bl*(size_t)DI + d;
  acc = fmaf(w.w, xp[0], acc);
  if (tt >= 1) acc = fmaf(w.z, xp[-DI],   acc);
  if (tt >= 2) acc = fmaf(w.y, xp[-2*DI], acc);
  if (tt >= 3) acc = fmaf(w.x, xp[-3*DI], acc);
  float sg = 1.f/(1.f + __expf(-acc));
  xc[idx] = acc * sg;
}

__global__ __launch_bounds__(256)
void zero_k(float* __restrict__ p)
{
  size_t i = ((size_t)blockIdx.x * 256 + threadIdx.x) * 4;
  *(float4*)(p + i) = make_float4(0.f, 0.f, 0.f, 0.f);
}

// ---------------- x_proj GEMM: (BLR,96) = xc(BLR,2048) * W(96,2048)^T --------
__global__ __launch_bounds__(256)
void xproj_k(const float* __restrict__ A, const float* __restrict__ W,
             float* __restrict__ out)
{
  __shared__ float As[16][132];
  __shared__ float Bs[16][100];
  const int m0  = blockIdx.x * 128;
  const int kc0 = blockIdx.y * 256;
  const int t  = threadIdx.x;
  const int tm = t >> 2;
  const int tk = (t & 3) << 2;
  const int tx = t & 15;
  const int ty = t >> 4;
  float acc[8][6];
  #pragma unroll
  for (int i = 0; i < 8; ++i)
    #pragma unroll
    for (int j = 0; j < 6; ++j) acc[i][j] = 0.f;

  for (int k0 = kc0; k0 < kc0 + 256; k0 += 16) {
    float4 a0 = *(const float4*)(A + (size_t)(m0 + tm) * DI + k0 + tk);
    float4 a1 = *(const float4*)(A + (size_t)(m0 + tm + 64) * DI + k0 + tk);
    float4 b0 = *(const float4*)(W + (size_t)tm * DI + k0 + tk);
    float4 b1 = make_float4(0.f,0.f,0.f,0.f);
    bool hasb1 = (tm < 32);
    if (hasb1) b1 = *(const float4*)(W + (size_t)(tm + 64) * DI + k0 + tk);
    __syncthreads();
    As[tk+0][tm] = a0.x; As[tk+1][tm] = a0.y; As[tk+2][tm] = a0.z; As[tk+3][tm] = a0.w;
    As[tk+0][tm+64] = a1.x; As[tk+1][tm+64] = a1.y; As[tk+2][tm+64] = a1.z; As[tk+3][tm+64] = a1.w;
    Bs[tk+0][tm] = b0.x; Bs[tk+1][tm] = b0.y; Bs[tk+2][tm] = b0.z; Bs[tk+3][tm] = b0.w;
    if (hasb1) {
      Bs[tk+0][tm+64] = b1.x; Bs[tk+1][tm+64] = b1.y; Bs[tk+2][tm+64] = b1.z; Bs[tk+3][tm+64] = b1.w;
    }
    __syncthreads();
    #pragma unroll
    for (int k = 0; k < 16; ++k) {
      float4 av0 = *(const float4*)&As[k][ty*8];
      float4 av1 = *(const float4*)&As[k][ty*8+4];
      float a[8] = {av0.x, av0.y, av0.z, av0.w, av1.x, av1.y, av1.z, av1.w};
      float2 p0 = *(const float2*)&Bs[k][tx*6];
      float2 p1 = *(const float2*)&Bs[k][tx*6+2];
      float2 p2 = *(const float2*)&Bs[k][tx*6+4];
      float b[6] = {p0.x, p0.y, p1.x, p1.y, p2.x, p2.y};
      #pragma unroll
      for (int i = 0; i < 8; ++i)
        #pragma unroll
        for (int j = 0; j < 6; ++j)
          acc[i][j] = fmaf(a[i], b[j], acc[i][j]);
    }
  }
  #pragma unroll
  for (int i = 0; i < 8; ++i)
    #pragma unroll
    for (int j = 0; j < 6; ++j)
      atomicAdd(&out[(size_t)(m0 + ty*8 + i) * 96 + tx*6 + j], acc[i][j]);
}

// ------- dt = softplus(dbl[:, :64] * Wdt^T + bdt) -> xd (stride DI) ----------
__global__ __launch_bounds__(256)
void dtproj_k(const float* __restrict__ dbl, const float* __restrict__ Wdt,
              const float* __restrict__ bdt, float* __restrict__ xd)
{
  const int bl0 = blockIdx.x * 32;
  const int d   = blockIdx.y * 256 + threadIdx.x;
  const int t   = threadIdx.x;
  __shared__ float rows[32][64];
  #pragma unroll
  for (int p = 0; p < 8; ++p) {
    int i = p*256 + t;
    int r = i >> 6, k = i & 63;
    rows[r][k] = dbl[(size_t)(bl0 + r) * 96 + k];
  }
  float4 w[16];
  #pragma unroll
  for (int q = 0; q < 16; ++q) w[q] = *(const float4*)(Wdt + (size_t)d*64 + q*4);
  float bias = bdt[d];
  __syncthreads();
  for (int r = 0; r < 32; ++r) {
    float s = bias;
    #pragma unroll
    for (int q = 0; q < 16; ++q) {
      float4 rv = *(const float4*)&rows[r][q*4];
      s = fmaf(rv.x, w[q].x, s); s = fmaf(rv.y, w[q].y, s);
      s = fmaf(rv.z, w[q].z, s); s = fmaf(rv.w, w[q].w, s);
    }
    float sp = (s > 20.f) ? s : log1pf(__expf(s));
    xd[(size_t)(bl0 + r) * DI + d] = sp;
  }
}

// ---------------- scan pass A: per-chunk end state (h0=0) + sum(dt) ----------
__global__ __launch_bounds__(256)
void scanA_k(const float* __restrict__ dt, const float* __restrict__ xc,
             const float* __restrict__ dbl, const float* __restrict__ A_log,
             float* __restrict__ hend, float* __restrict__ Sbuf)
{
  const int d = blockIdx.x * 256 + threadIdx.x;
  const int c = blockIdx.y;
  const int b = blockIdx.z;
  const int t = threadIdx.x;
  __shared__ float Bsh[CHK][NST];
  #pragma unroll
  for (int p = 0; p < 4; ++p) {
    int i = p*256 + t;
    int s = i >> 4, n = i & 15;
    Bsh[s][n] = dbl[(size_t)(b*LL + c*CHK + s) * 96 + 64 + n];
  }
  float Ar[16];
  #pragma unroll
  for (int q = 0; q < 4; ++q) {
    float4 al = *(const float4*)(A_log + (size_t)d*16 + q*4);
    Ar[q*4+0] = -__expf(al.x); Ar[q*4+1] = -__expf(al.y);
    Ar[q*4+2] = -__expf(al.z); Ar[q*4+3] = -__expf(al.w);
  }
  __syncthreads();
  float h[16];
  #pragma unroll
  for (int n = 0; n < 16; ++n) h[n] = 0.f;
  float S = 0.f;
  size_t base = ((size_t)b*LL + c*CHK) * DI + d;
  for (int s = 0; s < CHK; ++s) {
    float dtv = dt[base + (size_t)s*DI];
    float xv  = xc[base + (size_t)s*DI];
    S += dtv;
    float dtx = dtv * xv;
    const float4* Bp = (const float4*)&Bsh[s][0];
    #pragma unroll
    for (int q = 0; q < 4; ++q) {
      float4 bv = Bp[q];
      h[q*4+0] = fmaf(__expf(dtv*Ar[q*4+0]), h[q*4+0], dtx*bv.x);
      h[q*4+1] = fmaf(__expf(dtv*Ar[q*4+1]), h[q*4+1], dtx*bv.y);
      h[q*4+2] = fmaf(__expf(dtv*Ar[q*4+2]), h[q*4+2], dtx*bv.z);
      h[q*4+3] = fmaf(__expf(dtv*Ar[q*4+3]), h[q*4+3], dtx*bv.w);
    }
  }
  size_t o = ((size_t)b*NCH + c) * DI + d;
  float4* hp = (float4*)(hend + o*16);
  hp[0] = make_float4(h[0],h[1],h[2],h[3]);
  hp[1] = make_float4(h[4],h[5],h[6],h[7]);
  hp[2] = make_float4(h[8],h[9],h[10],h[11]);
  hp[3] = make_float4(h[12],h[13],h[14],h[15]);
  Sbuf[o] = S;
}

// ---------------- scan pass B: stitch chunk boundaries -----------------------
__global__ __launch_bounds__(256)
void scanB_k(float* __restrict__ hend, const float* __restrict__ Sbuf,
             const float* __restrict__ A_log)
{
  int idx = blockIdx.x * 256 + threadIdx.x;   // BB*DI*16
  int n = idx & 15;
  int d = (idx >> 4) & (DI-1);
  int b = idx >> 15;
  float An = -__expf(A_log[(size_t)d*16 + n]);
  float carry = 0.f;
  for (int c = 0; c < NCH-1; ++c) {
    size_t o = ((size_t)b*NCH + c) * DI + d;
    float he = hend[o*16 + n];
    float Sc = Sbuf[o];
    carry = fmaf(__expf(An*Sc), carry, he);
    hend[o*16 + n] = carry;
  }
}

// ---- scan pass C: replay with true h0, fuse epilogue, emit bf16 hi/lo -------
// Reads z (f32) from zf and writes out_z hi/lo bf16 into Zu = SAME buffer,
// panel-interleaved per 64 d's: [hi x64 | lo x64]. Each wave only touches the
// bytes of the z values its own 64 lanes just read -> race-free.
__global__ __launch_bounds__(256)
void scanC_k(const float* __restrict__ dt, const float* __restrict__ xc,
             const float* zf, u16* Zu,
             const float* __restrict__ dbl, const float* __restrict__ A_log,
             const float* __restrict__ Dv, const float* __restrict__ hend)
{
  const int d = blockIdx.x * 256 + threadIdx.x;
  const int c = blockIdx.y;
  const int b = blockIdx.z;
  const int t = threadIdx.x;
  __shared__ float Bsh[CHK][NST];
  __shared__ float Csh[CHK][NST];
  #pragma unroll
  for (int p = 0; p < 4; ++p) {
    int i = p*256 + t;
    int s = i >> 4, n = i & 15;
    size_t row = (size_t)(b*LL + c*CHK + s) * 96;
    Bsh[s][n] = dbl[row + 64 + n];
    Csh[s][n] = dbl[row + 80 + n];
  }
  float Ar[16];
  #pragma unroll
  for (int q = 0; q < 4; ++q) {
    float4 al = *(const float4*)(A_log + (size_t)d*16 + q*4);
    Ar[q*4+0] = -__expf(al.x); Ar[q*4+1] = -__expf(al.y);
    Ar[q*4+2] = -__expf(al.z); Ar[q*4+3] = -__expf(al.w);
  }
  float Dd = Dv[d];
  float h[16];
  if (c == 0) {
    #pragma unroll
    for (int n = 0; n < 16; ++n) h[n] = 0.f;
  } else {
    size_t o = ((size_t)b*NCH + (c-1)) * DI + d;
    const float4* hp = (const float4*)(hend + o*16);
    float4 h0 = hp[0], h1 = hp[1], h2 = hp[2], h3 = hp[3];
    h[0]=h0.x; h[1]=h0.y; h[2]=h0.z; h[3]=h0.w;
    h[4]=h1.x; h[5]=h1.y; h[6]=h1.z; h[7]=h1.w;
    h[8]=h2.x; h[9]=h2.y; h[10]=h2.z; h[11]=h2.w;
    h[12]=h3.x; h[13]=h3.y; h[14]=h3.z; h[15]=h3.w;
  }
  __syncthreads();
  size_t base = ((size_t)b*LL + c*CHK) * DI + d;
  for (int s = 0; s < CHK; ++s) {
    float dtv = dt[base + (size_t)s*DI];
    float xv  = xc[base + (size_t)s*DI];
    float zv  = zf[base + (size_t)s*DI];
    float dtx = dtv * xv;
    float y = 0.f;
    const float4* Bp = (const float4*)&Bsh[s][0];
    const float4* Cp = (const float4*)&Csh[s][0];
    #pragma unroll
    for (int q = 0; q < 4; ++q) {
      float4 bv = Bp[q], cv = Cp[q];
      h[q*4+0] = fmaf(__expf(dtv*Ar[q*4+0]), h[q*4+0], dtx*bv.x); y = fmaf(h[q*4+0], cv.x, y);
      h[q*4+1] = fmaf(__expf(dtv*Ar[q*4+1]), h[q*4+1], dtx*bv.y); y = fmaf(h[q*4+1], cv.y, y);
      h[q*4+2] = fmaf(__expf(dtv*Ar[q*4+2]), h[q*4+2], dtx*bv.z); y = fmaf(h[q*4+2], cv.z, y);
      h[q*4+3] = fmaf(__expf(dtv*Ar[q*4+3]), h[q*4+3], dtx*bv.w); y = fmaf(h[q*4+3], cv.w, y);
    }
    y = fmaf(xv, Dd, y);
    float sg = 1.f/(1.f + __expf(-zv));
    float oz = y * (zv * sg);
    u16 hi = f2bf(oz);
    u16 lo = f2bf(oz - bf2f(hi));
    size_t row = (size_t)b*LL + c*CHK + s;
    size_t zb = row*(size_t)4096 + (size_t)(d >> 6)*128 + (d & 63);
    Zu[zb]      = hi;
    Zu[zb + 64] = lo;
  }
}

extern "C" void kernel_launch(void* const* d_in, const int* in_sizes, int n_in,
                              void* d_out, int out_size, void* d_ws, size_t ws_size,
                              hipStream_t stream)
{
  const float* hs   = (const float*)d_in[0];
  const float* Win  = (const float*)d_in[1];
  const float* cw   = (const float*)d_in[2];
  const float* cb   = (const float*)d_in[3];
  const float* Wx   = (const float*)d_in[4];
  const float* Wdt  = (const float*)d_in[5];
  const float* bdt  = (const float*)d_in[6];
  const float* Alog = (const float*)d_in[7];
  const float* Dv   = (const float*)d_in[8];
  const float* Wout = (const float*)d_in[9];
  float* out = (float*)d_out;

  // ws layout (192 MiB total, same as the passing round):
  //   [0,64M):   xd  = x (GEMM1 out) -> dt (dtproj out)
  //   [64,128M): z   = z (GEMM1 out) -> Zu (out_z bf16 hi/lo, panel-interleaved)
  //   [128,192M):xc region: A1'(32M)+W1'(16M) -> xc(f32) -> W2'(8M)
  float* ws = (float*)d_ws;
  float* xd = ws;                                   // BLR*DI f32
  float* z  = ws + (size_t)BLR*DI;                  // BLR*DI f32
  float* xc = ws + (size_t)2*BLR*DI;                // BLR*DI f32

  u16* A1u = (u16*)xc;                              // 8192 x [hi1024|lo1024]
  u16* W1u = A1u + (size_t)BLR*2048;                // 4096 x [hi1024|lo1024]
  u16* W2u = (u16*)xc;                              // 1024 x [hi2048|lo2048]
  u16* Zu  = (u16*)z;                               // 8192 x 4096 (panel)

  // d_out scratch (consumed before final GEMM overwrites it)
  float* hend = out;                                // BB*NCH*DI*16
  float* Sb   = hend + (size_t)BB*NCH*DI*NST;       // BB*NCH*DI
  float* dbl  = Sb + (size_t)BB*NCH*DI;             // BLR*96

  // 1) bf16 hi/lo splits for GEMM1
  convsplit_k<<<8192, 256, 0, stream>>>(hs,  A1u, 8);
  convsplit_k<<<4096, 256, 0, stream>>>(Win, W1u, 8);
  // 2) xz = hs * Win^T via MFMA bf16x3; x-half -> xd, z-half -> z
  gemm_mfma<false><<<dim3(16, 64), 256, 0, stream>>>(A1u, W1u, xd, 4096, 4096, 2048, 1024);
  gemm_mfma<false><<<dim3(16, 64), 256, 0, stream>>>(A1u, W1u + (size_t)2048*2048, z, 4096, 4096, 2048, 1024);
  // 3) conv + silu -> xc (overwrites A1'/W1', now dead)
  conv_silu_k<<<(BLR*DI)/256, 256, 0, stream>>>(xd, cw, cb, xc);
  // 4) dbl = xc * Wx^T
  zero_k<<<(BLR*96)/1024, 256, 0, stream>>>(dbl);
  xproj_k<<<dim3(BLR/128, 8), 256, 0, stream>>>(xc, Wx, dbl);
  // 5) dt -> xd (x dead)
  dtproj_k<<<dim3(BLR/32, DI/256), 256, 0, stream>>>(dbl, Wdt, bdt, xd);
  // 6) chunked scan
  scanA_k<<<dim3(DI/256, NCH, BB), 256, 0, stream>>>(xd, xc, dbl, Alog, hend, Sb);
  scanB_k<<<(BB*DI*NST)/256, 256, 0, stream>>>(hend, Sb, Alog);
  scanC_k<<<dim3(DI/256, NCH, BB), 256, 0, stream>>>(xd, xc, z, Zu, dbl, Alog, Dv, hend);
  // 7) W2' split (xc dead after scanC)
  convsplit_k<<<2048, 256, 0, stream>>>(Wout, W2u, 9);
  // 8) out = out_z * Wout^T via MFMA bf16x3 (A panel-interleaved)
  gemm_mfma<true><<<dim3(8, 64), 256, 0, stream>>>(Zu, W2u, out, 8192, 8192, 1024, 2048);
}

// Round 4
// 664.350 us; speedup vs baseline: 2.4216x; 1.2241x over previous
//
#include <hip/hip_runtime.h>
#include <hip/hip_bf16.h>
#include <cstddef>
#include <cstdint>

#define BB 2
#define LL 4096
#define DM 1024
#define DI 2048
#define NST 16
#define BLR (BB*LL)      // 8192 rows of (b,l)
#define NCH 64           // chunks for the scan
#define CHK (LL/NCH)     // 64 steps per chunk

typedef __attribute__((ext_vector_type(8))) short bf16x8;   // 8 bf16 (4 VGPRs)
typedef __attribute__((ext_vector_type(4))) float f32x4;
typedef unsigned short u16;

__device__ __forceinline__ u16 f2bf(float x) {
  __hip_bfloat16 h = __float2bfloat16(x);
  return __builtin_bit_cast(u16, h);
}
__device__ __forceinline__ float bf2f(u16 u) {
  return __bfloat162float(__builtin_bit_cast(__hip_bfloat16, u));
}

__device__ __forceinline__ void gload_lds16(const void* g, void* l) {
  __builtin_amdgcn_global_load_lds((const __attribute__((address_space(1))) void*)g,
                                   (__attribute__((address_space(3))) void*)l, 16, 0, 0);
}

// ---- split fp32 -> [hi | lo] bf16 per row; dst row = 2K u16 ----------------
__global__ __launch_bounds__(256)
void convsplit_k(const float* __restrict__ src, u16* __restrict__ dst, int kshift)
{
  size_t i = (size_t)blockIdx.x * 256 + threadIdx.x;   // one per 4 floats
  float4 v = *(const float4*)(src + i*4);
  size_t row = i >> kshift;
  int c4 = (int)(i & ((1u << kshift) - 1));
  int K = 4 << kshift;
  u16 h0 = f2bf(v.x), h1 = f2bf(v.y), h2 = f2bf(v.z), h3 = f2bf(v.w);
  u16 l0 = f2bf(v.x - bf2f(h0)), l1 = f2bf(v.y - bf2f(h1));
  u16 l2 = f2bf(v.z - bf2f(h2)), l3 = f2bf(v.w - bf2f(h3));
  u16* p = dst + row*(size_t)(2*K) + (size_t)c4*4;
  *(ushort4*)p       = make_ushort4(h0, h1, h2, h3);
  *(ushort4*)(p + K) = make_ushort4(l0, l1, l2, l3);
}

// ---- MFMA GEMM: C[M,N] = A*B^T with bf16x3 compensation ---------------------
// A rows: plain [hi(Kfull) | lo(Kfull)] (APANEL=false) or panel-interleaved
//   per 64-k panel [hi x64 | lo x64] (APANEL=true); row stride ldaB bytes.
// B rows: plain [hi(Kfull) | lo(Kfull)], row stride ldbB bytes.
// 3 passes: (Ahi,Bhi), (Alo,Bhi), (Ahi,Blo). Tile 128x128, BK=64, 4 waves.
// Split-K via blockIdx.z (chunk = Kseg); ATOMIC -> atomicAdd epilogue.
template<bool APANEL, bool ATOMIC>
__global__ __launch_bounds__(256)
void gemm_mfma(const u16* __restrict__ Ab, const u16* __restrict__ Bb,
               float* __restrict__ C, int ldaB, int ldbB, int ldc,
               int Kfull, int Kseg)
{
  __shared__ __align__(16) u16 lds[16384];   // 32 KB: A [0,16K), B [16K,32K)
  // XCD-contiguous tile swizzle (requires nwg % 8 == 0)
  const int nx = gridDim.x, ny = gridDim.y, nz = gridDim.z;
  const int nwg = nx*ny*nz;
  int lin = blockIdx.x + nx*(blockIdx.y + ny*blockIdx.z);
  int tile = (!(nwg & 7)) ? ((lin & 7)*(nwg >> 3) + (lin >> 3)) : lin;
  const int bx = tile % nx;
  const int r1 = tile / nx;
  const int by = r1 % ny;
  const int bz = r1 / ny;

  const int t = threadIdx.x;
  const int lane = t & 63, wave = t >> 6;
  const int wm = wave >> 1, wn = wave & 1;
  const int m0 = by << 7, n0 = bx << 7;
  const int kbase = bz * Kseg;

  const int r0  = t >> 3;
  const int csw = ((t & 7) ^ (r0 & 7)) << 4;   // byte offset of source chunk

  f32x4 acc[4][4];
  #pragma unroll
  for (int m = 0; m < 4; ++m)
    #pragma unroll
    for (int n = 0; n < 4; ++n) acc[m][n] = (f32x4){0.f, 0.f, 0.f, 0.f};

  char* ldsA = (char*)lds;
  char* ldsB = (char*)lds + 16384;

  const int aSegStride = APANEL ? 128 : Kfull*2;  // byte offset of lo-segment
  const int aKmul      = APANEL ? 4 : 2;          // row bytes per unit k0

  const int segAv[3] = {0, 1, 0};
  const int segBv[3] = {0, 0, 1};

  for (int pass = 0; pass < 3; ++pass) {
    const size_t aOff0 = (size_t)segAv[pass] * (size_t)aSegStride;
    const size_t bOff0 = (size_t)segBv[pass] * (size_t)(Kfull*2);
    for (int k0 = kbase; k0 < kbase + Kseg; k0 += 64) {
      __syncthreads();   // previous compute done before LDS overwrite
      #pragma unroll
      for (int j = 0; j < 4; ++j) {
        const char* ga = (const char*)Ab + (size_t)(m0 + j*32 + r0)*ldaB
                         + aOff0 + (size_t)k0*aKmul + csw;
        gload_lds16(ga, ldsA + j*4096 + wave*1024);
      }
      #pragma unroll
      for (int j = 0; j < 4; ++j) {
        const char* gb = (const char*)Bb + (size_t)(n0 + j*32 + r0)*ldbB
                         + bOff0 + (size_t)k0*2 + csw;
        gload_lds16(gb, ldsB + j*4096 + wave*1024);
      }
      __syncthreads();   // vmcnt(0) drained -> LDS tiles ready
      #pragma unroll
      for (int kk = 0; kk < 2; ++kk) {
        const int kb = (kk*64 + ((lane >> 4) << 4)) ^ ((lane & 7) << 4);
        bf16x8 a[4], b[4];
        #pragma unroll
        for (int m = 0; m < 4; ++m)
          a[m] = *(const bf16x8*)(ldsA + (wm*64 + m*16 + (lane & 15))*128 + kb);
        #pragma unroll
        for (int n = 0; n < 4; ++n)
          b[n] = *(const bf16x8*)(ldsB + (wn*64 + n*16 + (lane & 15))*128 + kb);
        #pragma unroll
        for (int m = 0; m < 4; ++m)
          #pragma unroll
          for (int n = 0; n < 4; ++n)
            acc[m][n] = __builtin_amdgcn_mfma_f32_16x16x32_bf16(a[m], b[n], acc[m][n], 0, 0, 0);
      }
    }
  }
  // epilogue: C/D layout col=lane&15, row=(lane>>4)*4+i
  const int rb = (lane >> 4) << 2;
  const int cb = lane & 15;
  #pragma unroll
  for (int m = 0; m < 4; ++m) {
    #pragma unroll
    for (int n = 0; n < 4; ++n) {
      int row = m0 + wm*64 + m*16 + rb;
      int col = n0 + wn*64 + n*16 + cb;
      #pragma unroll
      for (int i = 0; i < 4; ++i) {
        if (ATOMIC) atomicAdd(&C[(size_t)(row + i)*ldc + col], acc[m][n][i]);
        else        C[(size_t)(row + i)*ldc + col] = acc[m][n][i];
      }
    }
  }
}

// ---- depthwise causal conv(4) + SiLU; x from xz cols [0,2048); out bf16 hi/lo
// xcu layout: row stride 4096 u16, per 64-d panel [hi x64 | lo x64].
__global__ __launch_bounds__(256)
void conv_silu_k(const float* __restrict__ xz, const float* __restrict__ cw,
                 const float* __restrict__ cb, u16* __restrict__ xcu)
{
  size_t idx = (size_t)blockIdx.x * 256 + threadIdx.x;   // over BLR*DI
  int d   = (int)(idx & (DI-1));
  size_t bl = idx >> 11;
  int tt  = (int)(bl & (LL-1));
  float4 w = *(const float4*)(cw + (size_t)d*4);
  float acc = cb[d];
  const float* xp = xz + bl*(size_t)4096 + d;
  acc = fmaf(w.w, xp[0], acc);
  if (tt >= 1) acc = fmaf(w.z, xp[-4096],   acc);
  if (tt >= 2) acc = fmaf(w.y, xp[-2*4096], acc);
  if (tt >= 3) acc = fmaf(w.x, xp[-3*4096], acc);
  float sg = 1.f/(1.f + __expf(-acc));
  float v = acc * sg;
  u16 hi = f2bf(v);
  u16 lo = f2bf(v - bf2f(hi));
  size_t o = bl*(size_t)4096 + (size_t)((d >> 6) << 7) + (d & 63);
  xcu[o]      = hi;
  xcu[o + 64] = lo;
}

__global__ __launch_bounds__(256)
void zero_k(float* __restrict__ p)
{
  size_t i = ((size_t)blockIdx.x * 256 + threadIdx.x) * 4;
  *(float4*)(p + i) = make_float4(0.f, 0.f, 0.f, 0.f);
}

// ------- dt = softplus(dbl[:, :64] * Wdt^T + bdt) -> x-cols of xz ------------
__global__ __launch_bounds__(256)
void dtproj_k(const float* __restrict__ dbl, const float* __restrict__ Wdt,
              const float* __restrict__ bdt, float* __restrict__ xz)
{
  const int bl0 = blockIdx.x * 32;
  const int d   = blockIdx.y * 256 + threadIdx.x;
  const int t   = threadIdx.x;
  __shared__ float rows[32][64];
  #pragma unroll
  for (int p = 0; p < 8; ++p) {
    int i = p*256 + t;
    int r = i >> 6, k = i & 63;
    rows[r][k] = dbl[(size_t)(bl0 + r) * 128 + k];
  }
  float4 w[16];
  #pragma unroll
  for (int q = 0; q < 16; ++q) w[q] = *(const float4*)(Wdt + (size_t)d*64 + q*4);
  float bias = bdt[d];
  __syncthreads();
  for (int r = 0; r < 32; ++r) {
    float s = bias;
    #pragma unroll
    for (int q = 0; q < 16; ++q) {
      float4 rv = *(const float4*)&rows[r][q*4];
      s = fmaf(rv.x, w[q].x, s); s = fmaf(rv.y, w[q].y, s);
      s = fmaf(rv.z, w[q].z, s); s = fmaf(rv.w, w[q].w, s);
    }
    float sp = (s > 20.f) ? s : log1pf(__expf(s));
    xz[(size_t)(bl0 + r) * 4096 + d] = sp;
  }
}

// ---------------- scan pass A: per-chunk end state (h0=0) + sum(dt) ----------
__global__ __launch_bounds__(256)
void scanA_k(const float* __restrict__ dt, const u16* __restrict__ xcu,
             const float* __restrict__ dbl, const float* __restrict__ A_log,
             float* __restrict__ hend, float* __restrict__ Sbuf)
{
  const int d = blockIdx.x * 256 + threadIdx.x;
  const int c = blockIdx.y;
  const int b = blockIdx.z;
  const int t = threadIdx.x;
  __shared__ float Bsh[CHK][NST];
  #pragma unroll
  for (int p = 0; p < 4; ++p) {
    int i = p*256 + t;
    int s = i >> 4, n = i & 15;
    Bsh[s][n] = dbl[(size_t)(b*LL + c*CHK + s) * 128 + 64 + n];
  }
  float Ar[16];
  #pragma unroll
  for (int q = 0; q < 4; ++q) {
    float4 al = *(const float4*)(A_log + (size_t)d*16 + q*4);
    Ar[q*4+0] = -__expf(al.x); Ar[q*4+1] = -__expf(al.y);
    Ar[q*4+2] = -__expf(al.z); Ar[q*4+3] = -__expf(al.w);
  }
  __syncthreads();
  float h[16];
  #pragma unroll
  for (int n = 0; n < 16; ++n) h[n] = 0.f;
  float S = 0.f;
  size_t rowb = (size_t)b*LL + c*CHK;
  size_t dtb = rowb*4096 + d;
  size_t xob = rowb*4096 + (size_t)((d >> 6) << 7) + (d & 63);
  for (int s = 0; s < CHK; ++s) {
    float dtv = dt[dtb + (size_t)s*4096];
    float xv  = bf2f(xcu[xob + (size_t)s*4096]) + bf2f(xcu[xob + (size_t)s*4096 + 64]);
    S += dtv;
    float dtx = dtv * xv;
    const float4* Bp = (const float4*)&Bsh[s][0];
    #pragma unroll
    for (int q = 0; q < 4; ++q) {
      float4 bv = Bp[q];
      h[q*4+0] = fmaf(__expf(dtv*Ar[q*4+0]), h[q*4+0], dtx*bv.x);
      h[q*4+1] = fmaf(__expf(dtv*Ar[q*4+1]), h[q*4+1], dtx*bv.y);
      h[q*4+2] = fmaf(__expf(dtv*Ar[q*4+2]), h[q*4+2], dtx*bv.z);
      h[q*4+3] = fmaf(__expf(dtv*Ar[q*4+3]), h[q*4+3], dtx*bv.w);
    }
  }
  size_t o = ((size_t)b*NCH + c) * DI + d;
  float4* hp = (float4*)(hend + o*16);
  hp[0] = make_float4(h[0],h[1],h[2],h[3]);
  hp[1] = make_float4(h[4],h[5],h[6],h[7]);
  hp[2] = make_float4(h[8],h[9],h[10],h[11]);
  hp[3] = make_float4(h[12],h[13],h[14],h[15]);
  Sbuf[o] = S;
}

// ---------------- scan pass B: stitch chunk boundaries -----------------------
__global__ __launch_bounds__(256)
void scanB_k(float* __restrict__ hend, const float* __restrict__ Sbuf,
             const float* __restrict__ A_log)
{
  int idx = blockIdx.x * 256 + threadIdx.x;   // BB*DI*16
  int n = idx & 15;
  int d = (idx >> 4) & (DI-1);
  int b = idx >> 15;
  float An = -__expf(A_log[(size_t)d*16 + n]);
  float carry = 0.f;
  for (int c = 0; c < NCH-1; ++c) {
    size_t o = ((size_t)b*NCH + c) * DI + d;
    float he = hend[o*16 + n];
    float Sc = Sbuf[o];
    carry = fmaf(__expf(An*Sc), carry, he);
    hend[o*16 + n] = carry;
  }
}

// ---- scan pass C: replay with true h0, fuse epilogue, emit bf16 hi/lo -------
// dt in x-cols of xz (f32), z in z-cols; out_z hi/lo bf16 overwrites the x-cols
// (panel-interleaved; each wave writes only bytes its own lanes just read).
// xzf and Zu alias -> neither is __restrict__.
__global__ __launch_bounds__(256)
void scanC_k(const float* xzf, u16* Zu, const u16* __restrict__ xcu,
             const float* __restrict__ dbl, const float* __restrict__ A_log,
             const float* __restrict__ Dv, const float* __restrict__ hend)
{
  const int d = blockIdx.x * 256 + threadIdx.x;
  const int c = blockIdx.y;
  const int b = blockIdx.z;
  const int t = threadIdx.x;
  __shared__ float Bsh[CHK][NST];
  __shared__ float Csh[CHK][NST];
  #pragma unroll
  for (int p = 0; p < 4; ++p) {
    int i = p*256 + t;
    int s = i >> 4, n = i & 15;
    size_t row = (size_t)(b*LL + c*CHK + s) * 128;
    Bsh[s][n] = dbl[row + 64 + n];
    Csh[s][n] = dbl[row + 80 + n];
  }
  float Ar[16];
  #pragma unroll
  for (int q = 0; q < 4; ++q) {
    float4 al = *(const float4*)(A_log + (size_t)d*16 + q*4);
    Ar[q*4+0] = -__expf(al.x); Ar[q*4+1] = -__expf(al.y);
    Ar[q*4+2] = -__expf(al.z); Ar[q*4+3] = -__expf(al.w);
  }
  float Dd = Dv[d];
  float h[16];
  if (c == 0) {
    #pragma unroll
    for (int n = 0; n < 16; ++n) h[n] = 0.f;
  } else {
    size_t o = ((size_t)b*NCH + (c-1)) * DI + d;
    const float4* hp = (const float4*)(hend + o*16);
    float4 h0 = hp[0], h1 = hp[1], h2 = hp[2], h3 = hp[3];
    h[0]=h0.x; h[1]=h0.y; h[2]=h0.z; h[3]=h0.w;
    h[4]=h1.x; h[5]=h1.y; h[6]=h1.z; h[7]=h1.w;
    h[8]=h2.x; h[9]=h2.y; h[10]=h2.z; h[11]=h2.w;
    h[12]=h3.x; h[13]=h3.y; h[14]=h3.z; h[15]=h3.w;
  }
  __syncthreads();
  size_t rowb = (size_t)b*LL + c*CHK;
  for (int s = 0; s < CHK; ++s) {
    size_t row = rowb + s;
    float dtv = xzf[row*4096 + d];
    float zv  = xzf[row*4096 + 2048 + d];
    float xv  = bf2f(xcu[row*4096 + (size_t)((d >> 6) << 7) + (d & 63)])
              + bf2f(xcu[row*4096 + (size_t)((d >> 6) << 7) + (d & 63) + 64]);
    float dtx = dtv * xv;
    float y = 0.f;
    const float4* Bp = (const float4*)&Bsh[s][0];
    const float4* Cp = (const float4*)&Csh[s][0];
    #pragma unroll
    for (int q = 0; q < 4; ++q) {
      float4 bv = Bp[q], cv = Cp[q];
      h[q*4+0] = fmaf(__expf(dtv*Ar[q*4+0]), h[q*4+0], dtx*bv.x); y = fmaf(h[q*4+0], cv.x, y);
      h[q*4+1] = fmaf(__expf(dtv*Ar[q*4+1]), h[q*4+1], dtx*bv.y); y = fmaf(h[q*4+1], cv.y, y);
      h[q*4+2] = fmaf(__expf(dtv*Ar[q*4+2]), h[q*4+2], dtx*bv.z); y = fmaf(h[q*4+2], cv.z, y);
      h[q*4+3] = fmaf(__expf(dtv*Ar[q*4+3]), h[q*4+3], dtx*bv.w); y = fmaf(h[q*4+3], cv.w, y);
    }
    y = fmaf(xv, Dd, y);
    float sg = 1.f/(1.f + __expf(-zv));
    float oz = y * (zv * sg);
    u16 hi = f2bf(oz);
    u16 lo = f2bf(oz - bf2f(hi));
    size_t zb = row*(size_t)8192 + (size_t)((d >> 6) << 7) + (d & 63);
    Zu[zb]      = hi;
    Zu[zb + 64] = lo;
  }
}

extern "C" void kernel_launch(void* const* d_in, const int* in_sizes, int n_in,
                              void* d_out, int out_size, void* d_ws, size_t ws_size,
                              hipStream_t stream)
{
  const float* hs   = (const float*)d_in[0];
  const float* Win  = (const float*)d_in[1];
  const float* cw   = (const float*)d_in[2];
  const float* cb   = (const float*)d_in[3];
  const float* Wx   = (const float*)d_in[4];
  const float* Wdt  = (const float*)d_in[5];
  const float* bdt  = (const float*)d_in[6];
  const float* Alog = (const float*)d_in[7];
  const float* Dv   = (const float*)d_in[8];
  const float* Wout = (const float*)d_in[9];
  float* out = (float*)d_out;

  // ws (192 MiB): xz [8192][4096] f32 (128M) | xcu [8192][4096] u16 (64M)
  // xcu region first holds A1u(32M)+W1u(16M), then xcu, then W2u(8M).
  float* xz  = (float*)d_ws;
  u16*   xcu = (u16*)(xz + (size_t)BLR*4096);
  u16*   A1u = xcu;
  u16*   W1u = A1u + (size_t)BLR*2048;
  u16*   W2u = xcu;
  u16*   Zu  = (u16*)xz;    // out_z bf16 panels in x-cols, row stride 8192 u16

  // d_out scratch (consumed before final GEMM): hend | Sb | dbl(128-pad) | Wxu
  float* hend = out;                                  // 4,194,304 f
  float* Sb   = hend + (size_t)BB*NCH*DI*NST;         //   262,144 f
  float* dbl  = Sb + (size_t)BB*NCH*DI;               // 1,048,576 f (8192x128)
  u16*   Wxu  = (u16*)(dbl + (size_t)BLR*128);        //   524,288 u16 (128x4096)

  // 1) bf16 hi/lo splits for GEMM1
  convsplit_k<<<8192, 256, 0, stream>>>(hs,  A1u, 8);
  convsplit_k<<<4096, 256, 0, stream>>>(Win, W1u, 8);
  // 2) xz = hs * Win^T (merged x|z), MFMA bf16x3
  gemm_mfma<false,false><<<dim3(32, 64, 1), 256, 0, stream>>>(A1u, W1u, xz, 4096, 4096, 4096, 1024, 1024);
  // 3) conv + silu -> xcu (bf16 hi/lo panels; overwrites A1u/W1u)
  conv_silu_k<<<(BLR*DI)/256, 256, 0, stream>>>(xz, cw, cb, xcu);
  // 4) dbl = xc * Wx^T via MFMA bf16x3, split-K=8 + atomics (dbl 128-padded)
  zero_k<<<(BLR*128)/1024, 256, 0, stream>>>(dbl);
  zero_k<<<(128*4096/2)/1024, 256, 0, stream>>>((float*)Wxu);
  convsplit_k<<<(96*2048/4)/256, 256, 0, stream>>>(Wx, Wxu, 9);
  gemm_mfma<true,true><<<dim3(1, 64, 8), 256, 0, stream>>>(xcu, Wxu, dbl, 8192, 8192, 128, 2048, 256);
  // 5) dt -> x-cols of xz (x dead after conv)
  dtproj_k<<<dim3(BLR/32, DI/256), 256, 0, stream>>>(dbl, Wdt, bdt, xz);
  // 6) chunked scan
  scanA_k<<<dim3(DI/256, NCH, BB), 256, 0, stream>>>(xz, xcu, dbl, Alog, hend, Sb);
  scanB_k<<<(BB*DI*NST)/256, 256, 0, stream>>>(hend, Sb, Alog);
  scanC_k<<<dim3(DI/256, NCH, BB), 256, 0, stream>>>(xz, Zu, xcu, dbl, Alog, Dv, hend);
  // 7) W2u split (xcu dead after scanC)
  convsplit_k<<<2048, 256, 0, stream>>>(Wout, W2u, 9);
  // 8) out = out_z * Wout^T, MFMA bf16x3 (A = Zu panels, row stride 16384 B)
  gemm_mfma<true,false><<<dim3(8, 64, 1), 256, 0, stream>>>(Zu, W2u, out, 16384, 8192, 1024, 2048, 2048);
}